// Round 14
// baseline (973.514 us; speedup 1.0000x reference)
//
#include <hip/hip_runtime.h>
#include <math.h>

#define TT 1024
#define DIN 128
#define HH 64
#define NN 16
#define EE 32
#define LL 3
#define BB 32
#define LOG2E 1.4426950408889634f

__device__ __forceinline__ float siluf(float x) { return x / (1.f + __expf(-x)); }
// raw v_exp_f32 (2^x)
__device__ __forceinline__ float exp2fast(float x) { return __builtin_amdgcn_exp2f(x); }

typedef __attribute__((ext_vector_type(8))) short bf16x8;
typedef __attribute__((ext_vector_type(4))) float f32x4;

// split fp32 into bf16 hi + bf16 lo (truncation; a ~= hi + lo, err ~2^-16 rel)
__device__ __forceinline__ void split2(float x, ushort& hi, ushort& lo) {
  unsigned u = __float_as_uint(x);
  hi = (ushort)(u >> 16);
  float rem = x - __uint_as_float((u >> 16) << 16);
  lo = (ushort)(__float_as_uint(rem) >> 16);
}

// pre-split weight buffer sizes (ushort counts)
#define WXZ_N 196608  // 4*3*256*64
#define WXD_N 73728   // 4*3*48*128 (n padded 36->48 with zeros)
#define WOUT_N 98304  // 4*3*64*128

// ---------------- K0: one-shot pre-split of all MFMA weights ----------------
__global__ __launch_bounds__(256) void k_presplit(
    const float* __restrict__ iprojW, const float* __restrict__ xprojW,
    const float* __restrict__ outW,
    ushort* __restrict__ WxzH, ushort* __restrict__ WxzL,
    ushort* __restrict__ WxdH, ushort* __restrict__ WxdL,
    ushort* __restrict__ WoH, ushort* __restrict__ WoL) {
  int idx = blockIdx.x * 256 + threadIdx.x;
  if (idx < WXZ_N) {
    ushort h, l;
    split2(iprojW[idx], h, l);
    WxzH[idx] = h; WxzL[idx] = l;
  }
  if (idx < WXD_N) {
    int k = idx & 127, r = (idx >> 7) % 48, bl = idx / (48 * 128);
    float v = (r < 36) ? xprojW[((size_t)(bl * 36 + r)) * 128 + k] : 0.f;
    ushort h, l;
    split2(v, h, l);
    WxdH[idx] = h; WxdL[idx] = l;
  }
  if (idx < WOUT_N) {
    ushort h, l;
    split2(outW[idx], h, l);
    WoH[idx] = h; WoL[idx] = l;
  }
}

// ---------------- K1: xz = h @ inW^T via split-bf16 MFMA (l==0 only) ----------------
__global__ __launch_bounds__(256) void k_xz(
    const float* __restrict__ x0, const float* __restrict__ x1,
    const float* __restrict__ x2, const float* __restrict__ x3,
    const ushort* __restrict__ WH, const ushort* __restrict__ WL,
    const float* __restrict__ inpW, const float* __restrict__ inpb,
    float* __restrict__ xr, float* __restrict__ zb, int br0) {
  __shared__ __align__(16) ushort Hh[64][72], Hl[64][72];  // h tile [t][k]
  const int tid = threadIdx.x;
  const int b  = blockIdx.y;
  const int t0 = blockIdx.x * 64;
  const int br = br0 + (b >> 5);
  {
    const int row = tid >> 2, c0 = (tid & 3) * 16;
    int bb = b & 31;
    const float* xp = (br == 0) ? x0 : (br == 1) ? x1 : (br == 2) ? x2 : x3;
    float xv = xp[bb * TT + t0 + row];
    #pragma unroll
    for (int q = 0; q < 4; ++q) {
      float4 w4 = *(const float4*)(inpW + br * HH + c0 + q * 4);
      float4 b4 = *(const float4*)(inpb + br * HH + c0 + q * 4);
      float4 hv;
      hv.x = xv * w4.x + b4.x; hv.y = xv * w4.y + b4.y;
      hv.z = xv * w4.z + b4.z; hv.w = xv * w4.w + b4.w;
      ushort h0,h1,h2,h3,l0,l1,l2,l3;
      split2(hv.x,h0,l0); split2(hv.y,h1,l1); split2(hv.z,h2,l2); split2(hv.w,h3,l3);
      *(ushort4*)&Hh[row][c0 + q*4] = make_ushort4(h0,h1,h2,h3);
      *(ushort4*)&Hl[row][c0 + q*4] = make_ushort4(l0,l1,l2,l3);
    }
  }
  __syncthreads();
  const int wave = tid >> 6, lane = tid & 63;
  const int quad = lane >> 4, l16 = lane & 15;
  const int nsub = (wave & 1) * 32, tsub = (wave >> 1) * 32;
  const size_t wbase = (size_t)(br * LL) * 256;
  for (int n0 = 0; n0 < 2 * DIN; n0 += 64) {
    f32x4 acc[2][2] = {};   // [n-frag][t-frag]
    #pragma unroll
    for (int k0 = 0; k0 < 64; k0 += 32) {
      bf16x8 Ah[2], Al[2], Bh[2], Bl[2];
      #pragma unroll
      for (int i = 0; i < 2; ++i) {
        size_t ro = (wbase + n0 + nsub + i * 16 + l16) * 64 + k0 + quad * 8;
        Ah[i] = *(const bf16x8*)(WH + ro);
        Al[i] = *(const bf16x8*)(WL + ro);
        Bh[i] = *(const bf16x8*)&Hh[tsub + i*16 + l16][k0 + quad*8];
        Bl[i] = *(const bf16x8*)&Hl[tsub + i*16 + l16][k0 + quad*8];
      }
      #pragma unroll
      for (int i = 0; i < 2; ++i)
        #pragma unroll
        for (int j = 0; j < 2; ++j) {
          acc[i][j] = __builtin_amdgcn_mfma_f32_16x16x32_bf16(Ah[i], Bh[j], acc[i][j], 0, 0, 0);
          acc[i][j] = __builtin_amdgcn_mfma_f32_16x16x32_bf16(Ah[i], Bl[j], acc[i][j], 0, 0, 0);
          acc[i][j] = __builtin_amdgcn_mfma_f32_16x16x32_bf16(Al[i], Bh[j], acc[i][j], 0, 0, 0);
        }
    }
    // D layout: col(t) = lane&15, row(n) = quad*4 + reg
    #pragma unroll
    for (int i = 0; i < 2; ++i) {
      #pragma unroll
      for (int r = 0; r < 4; ++r) {
        int n = n0 + nsub + i*16 + quad*4 + r;
        float* dst = (n < DIN) ? (xr + ((size_t)b * DIN + n) * TT)
                               : (zb + ((size_t)b * DIN + (n - DIN)) * TT);
        #pragma unroll
        for (int j = 0; j < 2; ++j)
          dst[t0 + tsub + j*16 + l16] = acc[i][j][r];
      }
    }
  }
}

// ---- K3: FUSED conv+silu + x_dbl GEMM + local chunk scan ----
// r14: 512-thread block (8 waves) at unchanged 44KB LDS -> 24 waves/CU (was
// 12). conv: 4 threads/d x 16t. GEMM: waves 0-3 do nf{0,1}, waves 4-7 do nf2.
// scan: 4 threads/d x 4 n-chains, width-4 shfl reduce. Formulas bit-identical;
// only the final n-reduction order changes (~1e-7 rel).
__global__ __launch_bounds__(512) void k_xds(
    const float* __restrict__ xr, const float* __restrict__ convW,
    const float* __restrict__ convb, const ushort* __restrict__ WH,
    const ushort* __restrict__ WL, const float* __restrict__ dtW,
    const float* __restrict__ dtb, const float* __restrict__ A_log,
    const float* __restrict__ D_skip,
    float* __restrict__ cd, float* __restrict__ Cm,
    float* __restrict__ Hloc, float* __restrict__ g, float* __restrict__ sdt,
    int br0, int l) {
  __shared__ __align__(16) float U[128][66];   // u tile fp32 [d][t]; stride 66
  __shared__ __align__(16) float Xs[36][68];   // x_dbl: 0..3 dt_r, 4..19 B, 20..35 C
  const int tid = threadIdx.x;
  const int b  = blockIdx.y;
  const int c  = blockIdx.x;           // chunk index
  const int t0 = c * 64;
  const int br = br0 + (b >> 5);
  const int wave = tid >> 6, lane = tid & 63;
  const int quad = lane >> 4, l16 = lane & 15;
  const int tw  = (wave & 3) * 16;     // wave's t-offset
  const int nfg = wave >> 2;           // 0: nf{0,1}; 1: nf{2}
  const size_t wb48 = (size_t)(br * LL + l) * 48 * 128;
  const int dd = tid >> 2, p4 = tid & 3;
  // ---- conv+silu: global->regs->U; 4 threads/d, 16 t each ----
  {
    const int tb = t0 + p4 * 16;                     // window start for this quarter
    const float* src = xr + ((size_t)b * DIN + dd) * TT + tb;
    float r[20];                                     // x[tb-4 .. tb+15]
    #pragma unroll
    for (int q = 0; q < 5; ++q) {
      float4 f = make_float4(0.f, 0.f, 0.f, 0.f);
      if (q > 0 || tb > 0) f = *(const float4*)(src - 4 + q * 4);
      r[q*4+0] = f.x; r[q*4+1] = f.y; r[q*4+2] = f.z; r[q*4+3] = f.w;
    }
    const int wb0 = (br * LL + l) * DIN + dd;
    const float* w = convW + (size_t)wb0 * 4;
    const float w0 = w[0], w1 = w[1], w2 = w[2], w3 = w[3];
    const float cb = convb[wb0];
    #pragma unroll
    for (int i = 0; i < 16; i += 2) {
      float o0 = siluf(r[i+1]*w0 + r[i+2]*w1 + r[i+3]*w2 + r[i+4]*w3 + cb);
      float o1 = siluf(r[i+2]*w0 + r[i+3]*w1 + r[i+4]*w2 + r[i+5]*w3 + cb);
      *(float2*)&U[dd][p4 * 16 + i] = make_float2(o0, o1);
    }
  }
  __syncthreads();   // barrier 1: U complete
  // ---- GEMM: x_dbl = W @ u; waves split the 3 n-frags ----
  f32x4 acc0 = {}, acc1 = {};
  #pragma unroll
  for (int k0 = 0; k0 < DIN; k0 += 32) {
    ushort bh[8], bl[8];
    #pragma unroll
    for (int j = 0; j < 8; ++j)
      split2(U[k0 + quad * 8 + j][tw + l16], bh[j], bl[j]);
    bf16x8 Bh = *(bf16x8*)bh, Bl = *(bf16x8*)bl;
    if (nfg == 0) {
      size_t ro0 = wb48 + (size_t)(l16) * 128 + k0 + quad * 8;
      size_t ro1 = wb48 + (size_t)(16 + l16) * 128 + k0 + quad * 8;
      bf16x8 Wh0 = *(const bf16x8*)(WH + ro0), Wl0 = *(const bf16x8*)(WL + ro0);
      bf16x8 Wh1 = *(const bf16x8*)(WH + ro1), Wl1 = *(const bf16x8*)(WL + ro1);
      acc0 = __builtin_amdgcn_mfma_f32_16x16x32_bf16(Wh0, Bh, acc0, 0, 0, 0);
      acc0 = __builtin_amdgcn_mfma_f32_16x16x32_bf16(Wh0, Bl, acc0, 0, 0, 0);
      acc0 = __builtin_amdgcn_mfma_f32_16x16x32_bf16(Wl0, Bh, acc0, 0, 0, 0);
      acc1 = __builtin_amdgcn_mfma_f32_16x16x32_bf16(Wh1, Bh, acc1, 0, 0, 0);
      acc1 = __builtin_amdgcn_mfma_f32_16x16x32_bf16(Wh1, Bl, acc1, 0, 0, 0);
      acc1 = __builtin_amdgcn_mfma_f32_16x16x32_bf16(Wl1, Bh, acc1, 0, 0, 0);
    } else {
      size_t ro2 = wb48 + (size_t)(32 + l16) * 128 + k0 + quad * 8;
      bf16x8 Wh2 = *(const bf16x8*)(WH + ro2), Wl2 = *(const bf16x8*)(WL + ro2);
      acc0 = __builtin_amdgcn_mfma_f32_16x16x32_bf16(Wh2, Bh, acc0, 0, 0, 0);
      acc0 = __builtin_amdgcn_mfma_f32_16x16x32_bf16(Wh2, Bl, acc0, 0, 0, 0);
      acc0 = __builtin_amdgcn_mfma_f32_16x16x32_bf16(Wl2, Bh, acc0, 0, 0, 0);
    }
  }
  // D layout: col(t) = l16, row(n) = quad*4 + r  ->  Xs[n][t]
  if (nfg == 0) {
    #pragma unroll
    for (int r = 0; r < 4; ++r) {
      Xs[quad * 4 + r][tw + l16]      = acc0[r];
      Xs[16 + quad * 4 + r][tw + l16] = acc1[r];
    }
  } else {
    #pragma unroll
    for (int r = 0; r < 4; ++r) {
      int n = 32 + quad * 4 + r;
      if (n < 36) Xs[n][tw + l16] = acc0[r];
    }
  }
  __syncthreads();   // barrier 2: Xs complete
  // Cm needed globally (k_scan2 stages it)
  if (tid < 256) {
    int n = tid >> 4, i0 = (tid & 15) * 4;
    *(float4*)(Cm + ((size_t)b * NN + n) * TT + t0 + i0) = *(float4*)&Xs[20 + n][i0];
  }
  // ---------------- scan phase: 4 threads per d, 4 n-states each ----------------
  const int n0s = p4 * 4;
  const int wbase = (br * LL + l) * DIN + dd;
  const float* wd = dtW + (size_t)wbase * 4;
  const float w0 = wd[0], w1 = wd[1], w2 = wd[2], w3 = wd[3];
  const float bias = dtb[wbase];
  float Ac[4];   // pre-scaled by log2e: exp(dt*A) == exp2(dt*Ac)
  #pragma unroll
  for (int j = 0; j < 4; ++j)
    Ac[j] = -LOG2E * __expf(A_log[(size_t)wbase * NN + n0s + j]);
  const float Dp = D_skip[wbase];
  float hst[4] = {0.f,0.f,0.f,0.f};
  float sd = 0.f;
  float* gp  = g  + ((size_t)b * DIN + dd) * TT + t0;
  float* cdp = cd + ((size_t)b * DIN + dd) * TT + t0;
  for (int t8 = 0; t8 < 64; t8 += 8) {
    // dt-source rows (broadcast reads; all lanes same address)
    float4 a0 = *(const float4*)&Xs[0][t8], a0b = *(const float4*)&Xs[0][t8 + 4];
    float4 a1 = *(const float4*)&Xs[1][t8], a1b = *(const float4*)&Xs[1][t8 + 4];
    float4 a2 = *(const float4*)&Xs[2][t8], a2b = *(const float4*)&Xs[2][t8 + 4];
    float4 a3 = *(const float4*)&Xs[3][t8], a3b = *(const float4*)&Xs[3][t8 + 4];
    float x0v[8] = {a0.x,a0.y,a0.z,a0.w,a0b.x,a0b.y,a0b.z,a0b.w};
    float x1v[8] = {a1.x,a1.y,a1.z,a1.w,a1b.x,a1b.y,a1b.z,a1b.w};
    float x2v[8] = {a2.x,a2.y,a2.z,a2.w,a2b.x,a2b.y,a2b.z,a2b.w};
    float x3v[8] = {a3.x,a3.y,a3.z,a3.w,a3b.x,a3b.y,a3b.z,a3b.w};
    float us[8];
    {
      float2 u0 = *(const float2*)&U[dd][t8];
      float2 u1 = *(const float2*)&U[dd][t8 + 2];
      float2 u2 = *(const float2*)&U[dd][t8 + 4];
      float2 u3 = *(const float2*)&U[dd][t8 + 6];
      us[0]=u0.x; us[1]=u0.y; us[2]=u1.x; us[3]=u1.y;
      us[4]=u2.x; us[5]=u2.y; us[6]=u3.x; us[7]=u3.y;
    }
    float dts[8], cds[8], du[8];
    #pragma unroll
    for (int s = 0; s < 8; ++s) {
      float sv = x0v[s]*w0 + x1v[s]*w1 + x2v[s]*w2 + x3v[s]*w3 + bias;
      float e = __expf(-fabsf(sv));
      float dtv = fmaxf(sv, 0.f) + __logf(1.f + e);   // softplus, same as before
      sd += dtv;
      dts[s] = dtv;
      cds[s] = sd;
      du[s] = dtv * us[s];
    }
    float acc8[8] = {0.f,0.f,0.f,0.f,0.f,0.f,0.f,0.f};
    #pragma unroll
    for (int j = 0; j < 4; ++j) {
      int n = n0s + j;
      float4 bq0 = *(const float4*)&Xs[4 + n][t8];
      float4 bq1 = *(const float4*)&Xs[4 + n][t8 + 4];
      float4 cq0 = *(const float4*)&Xs[20 + n][t8];
      float4 cq1 = *(const float4*)&Xs[20 + n][t8 + 4];
      float Bv[8] = {bq0.x,bq0.y,bq0.z,bq0.w,bq1.x,bq1.y,bq1.z,bq1.w};
      float Cv[8] = {cq0.x,cq0.y,cq0.z,cq0.w,cq1.x,cq1.y,cq1.z,cq1.w};
      float hj = hst[j], an = Ac[j];
      #pragma unroll
      for (int s = 0; s < 8; ++s) {
        hj = exp2fast(dts[s] * an) * hj + du[s] * Bv[s];
        acc8[s] += hj * Cv[s];
      }
      hst[j] = hj;
    }
    #pragma unroll
    for (int s = 0; s < 8; ++s) {
      float t1  = acc8[s] + __shfl_xor(acc8[s], 1, 4);
      float tot = t1 + __shfl_xor(t1, 2, 4);
      acc8[s] = tot + Dp * us[s];
    }
    if (p4 == 0) {
      *(float4*)(gp + t8)      = make_float4(acc8[0], acc8[1], acc8[2], acc8[3]);
      *(float4*)(gp + t8 + 4)  = make_float4(acc8[4], acc8[5], acc8[6], acc8[7]);
      *(float4*)(cdp + t8)     = make_float4(cds[0], cds[1], cds[2], cds[3]);
      *(float4*)(cdp + t8 + 4) = make_float4(cds[4], cds[5], cds[6], cds[7]);
    }
  }
  {
    float* hp = Hloc + (((size_t)b * DIN + dd) * 16 + c) * 16 + n0s;
    *(float4*)hp = make_float4(hst[0], hst[1], hst[2], hst[3]);
  }
  if (p4 == 0) sdt[((size_t)b * DIN + dd) * 16 + c] = sd;
}

// ---- K4c: combine (from Hloc + sdt) + parallel correction; reads precomputed cd ----
__global__ __launch_bounds__(256) void k_scan2(
    const float* __restrict__ cdc, const float* __restrict__ Cm,
    const float* __restrict__ A_log, const float* __restrict__ Hloc,
    const float* __restrict__ sdt, float* __restrict__ g, int br0, int l) {
  __shared__ __align__(16) float Cl[16][68];
  __shared__ __align__(16) float HinL[32][16];
  const int bx  = blockIdx.x;
  const int b   = bx / 60;
  const int rem = bx % 60;
  const int c   = (rem >> 2) + 1;   // 1..15
  const int dq  = rem & 3;
  const int tid = threadIdx.x;
  const int br  = br0 + (b >> 5);
  {
    int row = tid >> 4, cc = (tid & 15) * 4;
    *(float4*)&Cl[row][cc] = *(const float4*)(Cm + ((size_t)b * NN + row) * TT + c * 64 + cc);
  }
  const int dloc = tid >> 3, tg = tid & 7;
  const int d  = dq * 32 + dloc;
  size_t off = ((size_t)b * DIN + d) * TT + c * 64 + tg * 8;
  float* gp = g + off;
  float4 y0 = *(const float4*)gp;
  float4 y1 = *(const float4*)(gp + 4);
  float4 cq0 = *(const float4*)(cdc + off);
  float4 cq1 = *(const float4*)(cdc + off + 4);
  {
    int n0 = (tid & 7) * 2;
    int wbase = (br * LL + l) * DIN + d;
    float a0 = -LOG2E * __expf(A_log[(size_t)wbase * NN + n0]);
    float a1 = -LOG2E * __expf(A_log[(size_t)wbase * NN + n0 + 1]);
    float h0 = 0.f, h1 = 0.f;
    const float* sp  = sdt + ((size_t)b * DIN + d) * 16;
    const float* hlb = Hloc + ((size_t)b * DIN + d) * 256;
    for (int cc = 0; cc < c; ++cc) {
      float sdv = sp[cc];
      float2 hl = *(const float2*)(hlb + cc * 16 + n0);
      h0 = exp2fast(a0 * sdv) * h0 + hl.x;
      h1 = exp2fast(a1 * sdv) * h1 + hl.y;
    }
    HinL[dloc][n0] = h0;
    HinL[dloc][n0 + 1] = h1;
  }
  __syncthreads();
  float cd8[8] = {cq0.x, cq0.y, cq0.z, cq0.w, cq1.x, cq1.y, cq1.z, cq1.w};
  const float* al = A_log + (size_t)((br * LL + l) * DIN + d) * NN;
  float Ac16[16];
  #pragma unroll
  for (int n = 0; n < 16; ++n) Ac16[n] = -LOG2E * __expf(al[n]);
  float y8[8] = {y0.x, y0.y, y0.z, y0.w, y1.x, y1.y, y1.z, y1.w};
  const int tbase = tg * 8;
  #pragma unroll
  for (int n = 0; n < 16; ++n) {
    float hv = HinL[dloc][n];
    float an = Ac16[n];
    #pragma unroll
    for (int s = 0; s < 8; ++s)
      y8[s] += Cl[n][tbase + s] * exp2fast(an * cd8[s]) * hv;
  }
  *(float4*)gp       = make_float4(y8[0], y8[1], y8[2], y8[3]);
  *(float4*)(gp + 4) = make_float4(y8[4], y8[5], y8[6], y8[7]);
}

// ---- K5b: FUSED k_out(l) + k_xz(l+1) ----
__global__ __launch_bounds__(256) void k_outxz(
    const float* __restrict__ graw, float* zb,
    const ushort* __restrict__ WoHp, const ushort* __restrict__ WoLp,
    const ushort* __restrict__ WxHp, const ushort* __restrict__ WxLp,
    float* __restrict__ xr, int br0, int l) {
  __shared__ __align__(16) ushort Bh_[64][72], Bl_[64][72];
  const int tid = threadIdx.x;
  const int b  = blockIdx.y;
  const int t0 = blockIdx.x * 64;
  const int br = br0 + (b >> 5);
  const int wave = tid >> 6, lane = tid & 63;
  const int quad = lane >> 4, l16 = lane & 15;
  const int hsub = (wave & 1) * 32, tsub = (wave >> 1) * 32;
  const size_t wbo = (size_t)(br * LL + l) * 64;
  // ---- GEMM1: h-tile = (y*silu(z)) @ outW^T (registers only) ----
  f32x4 acc[2][2] = {};   // [hh-frag][t-frag]
  for (int k0 = 0; k0 < DIN; k0 += 64) {
    __syncthreads();
    {
      int row = tid >> 2, c0 = (tid & 3) * 16;
      #pragma unroll
      for (int q = 0; q < 4; ++q) {
        size_t off = ((size_t)b * DIN + k0 + row) * TT + t0 + c0 + q * 4;
        float4 gv = *(const float4*)(graw + off);
        float4 zv = *(const float4*)(zb + off);
        float a0 = gv.x * siluf(zv.x), a1 = gv.y * siluf(zv.y);
        float a2 = gv.z * siluf(zv.z), a3 = gv.w * siluf(zv.w);
        ushort h0,h1,h2,h3,l0,l1,l2,l3;
        split2(a0,h0,l0); split2(a1,h1,l1); split2(a2,h2,l2); split2(a3,h3,l3);
        *(ushort4*)&Bh_[row][c0 + q*4] = make_ushort4(h0,h1,h2,h3);
        *(ushort4*)&Bl_[row][c0 + q*4] = make_ushort4(l0,l1,l2,l3);
      }
    }
    __syncthreads();
    #pragma unroll
    for (int kk = 0; kk < 64; kk += 32) {
      bf16x8 Ahf[2], Alf[2], Bhf[2], Blf[2];
      #pragma unroll
      for (int i = 0; i < 2; ++i) {
        size_t ro = (wbo + hsub + i * 16 + l16) * 128 + k0 + kk + quad * 8;
        Ahf[i] = *(const bf16x8*)(WoHp + ro);
        Alf[i] = *(const bf16x8*)(WoLp + ro);
        Bhf[i] = *(const bf16x8*)&Bh_[tsub + i*16 + l16][kk + quad*8];
        Blf[i] = *(const bf16x8*)&Bl_[tsub + i*16 + l16][kk + quad*8];
      }
      #pragma unroll
      for (int i = 0; i < 2; ++i)
        #pragma unroll
        for (int j = 0; j < 2; ++j) {
          acc[i][j] = __builtin_amdgcn_mfma_f32_16x16x32_bf16(Ahf[i], Bhf[j], acc[i][j], 0, 0, 0);
          acc[i][j] = __builtin_amdgcn_mfma_f32_16x16x32_bf16(Ahf[i], Blf[j], acc[i][j], 0, 0, 0);
          acc[i][j] = __builtin_amdgcn_mfma_f32_16x16x32_bf16(Alf[i], Bhf[j], acc[i][j], 0, 0, 0);
        }
    }
  }
  __syncthreads();   // all GEMM1 LDS reads complete -> Bh_/Bl_ reusable
  // ---- write h tile (bf16 split) into Bh_/Bl_ as Hh[t][hh] ----
  #pragma unroll
  for (int i = 0; i < 2; ++i) {
    int hh0 = hsub + i*16 + quad*4;
    #pragma unroll
    for (int j = 0; j < 2; ++j) {
      int t = tsub + j*16 + l16;
      ushort h0,h1,h2,h3,l0,l1,l2,l3;
      split2(acc[i][j][0],h0,l0); split2(acc[i][j][1],h1,l1);
      split2(acc[i][j][2],h2,l2); split2(acc[i][j][3],h3,l3);
      *(ushort2*)&Bh_[t][hh0]     = make_ushort2(h0,h1);
      *(ushort2*)&Bh_[t][hh0 + 2] = make_ushort2(h2,h3);
      *(ushort2*)&Bl_[t][hh0]     = make_ushort2(l0,l1);
      *(ushort2*)&Bl_[t][hh0 + 2] = make_ushort2(l2,l3);
    }
  }
  __syncthreads();
  // ---- GEMM2: xz(l+1) = h @ inprojW(l+1)^T ----
  const size_t wbase = (size_t)(br * LL + (l + 1)) * 256;
  const int nsub = hsub;
  for (int n0 = 0; n0 < 2 * DIN; n0 += 64) {
    f32x4 a2[2][2] = {};
    #pragma unroll
    for (int k0 = 0; k0 < 64; k0 += 32) {
      bf16x8 Ah[2], Al[2], Bh[2], Bl[2];
      #pragma unroll
      for (int i = 0; i < 2; ++i) {
        size_t ro = (wbase + n0 + nsub + i * 16 + l16) * 64 + k0 + quad * 8;
        Ah[i] = *(const bf16x8*)(WxHp + ro);
        Al[i] = *(const bf16x8*)(WxLp + ro);
        Bh[i] = *(const bf16x8*)&Bh_[tsub + i*16 + l16][k0 + quad*8];
        Bl[i] = *(const bf16x8*)&Bl_[tsub + i*16 + l16][k0 + quad*8];
      }
      #pragma unroll
      for (int i = 0; i < 2; ++i)
        #pragma unroll
        for (int j = 0; j < 2; ++j) {
          a2[i][j] = __builtin_amdgcn_mfma_f32_16x16x32_bf16(Ah[i], Bh[j], a2[i][j], 0, 0, 0);
          a2[i][j] = __builtin_amdgcn_mfma_f32_16x16x32_bf16(Ah[i], Bl[j], a2[i][j], 0, 0, 0);
          a2[i][j] = __builtin_amdgcn_mfma_f32_16x16x32_bf16(Al[i], Bh[j], a2[i][j], 0, 0, 0);
        }
    }
    #pragma unroll
    for (int i = 0; i < 2; ++i) {
      #pragma unroll
      for (int r = 0; r < 4; ++r) {
        int n = n0 + nsub + i*16 + quad*4 + r;
        float* dst = (n < DIN) ? (xr + ((size_t)b * DIN + n) * TT)
                               : (zb + ((size_t)b * DIN + (n - DIN)) * TT);
        #pragma unroll
        for (int j = 0; j < 2; ++j)
          dst[t0 + tsub + j*16 + l16] = a2[i][j][r];
      }
    }
  }
}

// ---------------- K5: h = (y * silu(z)) @ outW^T (l==2 only) ----------------
__global__ __launch_bounds__(256) void k_out(
    const float* __restrict__ graw, const float* __restrict__ zb,
    const ushort* __restrict__ WH, const ushort* __restrict__ WL,
    float* __restrict__ h, int br0, int l) {
  __shared__ __align__(16) ushort Bh_[64][72], Bl_[64][72];  // act tile [d][t]
  const int tid = threadIdx.x;
  const int b  = blockIdx.y;
  const int t0 = blockIdx.x * 64;
  const int br = br0 + (b >> 5);
  const int wave = tid >> 6, lane = tid & 63;
  const int quad = lane >> 4, l16 = lane & 15;
  const int hsub = (wave & 1) * 32, tsub = (wave >> 1) * 32;
  const size_t wb = (size_t)(br * LL + l) * 64;
  f32x4 acc[2][2] = {};   // [hh-frag][t-frag]
  for (int k0 = 0; k0 < DIN; k0 += 64) {
    __syncthreads();
    {
      int row = tid >> 2, c0 = (tid & 3) * 16;
      #pragma unroll
      for (int q = 0; q < 4; ++q) {
        size_t off = ((size_t)b * DIN + k0 + row) * TT + t0 + c0 + q * 4;
        float4 gv = *(const float4*)(graw + off);
        float4 zv = *(const float4*)(zb + off);
        float a0 = gv.x * siluf(zv.x), a1 = gv.y * siluf(zv.y);
        float a2 = gv.z * siluf(zv.z), a3 = gv.w * siluf(zv.w);
        ushort h0,h1,h2,h3,l0,l1,l2,l3;
        split2(a0,h0,l0); split2(a1,h1,l1); split2(a2,h2,l2); split2(a3,h3,l3);
        *(ushort4*)&Bh_[row][c0 + q*4] = make_ushort4(h0,h1,h2,h3);
        *(ushort4*)&Bl_[row][c0 + q*4] = make_ushort4(l0,l1,l2,l3);
      }
    }
    __syncthreads();
    #pragma unroll
    for (int kk = 0; kk < 64; kk += 32) {
      bf16x8 Ahf[2], Alf[2], Bhf[2], Blf[2];
      #pragma unroll
      for (int i = 0; i < 2; ++i) {
        size_t ro = (wb + hsub + i * 16 + l16) * 128 + k0 + kk + quad * 8;
        Ahf[i] = *(const bf16x8*)(WH + ro);
        Alf[i] = *(const bf16x8*)(WL + ro);
        Bhf[i] = *(const bf16x8*)&Bh_[tsub + i*16 + l16][kk + quad*8];
        Blf[i] = *(const bf16x8*)&Bl_[tsub + i*16 + l16][kk + quad*8];
      }
      #pragma unroll
      for (int i = 0; i < 2; ++i)
        #pragma unroll
        for (int j = 0; j < 2; ++j) {
          acc[i][j] = __builtin_amdgcn_mfma_f32_16x16x32_bf16(Ahf[i], Bhf[j], acc[i][j], 0, 0, 0);
          acc[i][j] = __builtin_amdgcn_mfma_f32_16x16x32_bf16(Ahf[i], Blf[j], acc[i][j], 0, 0, 0);
          acc[i][j] = __builtin_amdgcn_mfma_f32_16x16x32_bf16(Alf[i], Bhf[j], acc[i][j], 0, 0, 0);
        }
    }
  }
  #pragma unroll
  for (int i = 0; i < 2; ++i) {
    int hh0 = hsub + i*16 + quad*4;
    #pragma unroll
    for (int j = 0; j < 2; ++j) {
      int t = t0 + tsub + j*16 + l16;
      *(f32x4*)(h + ((size_t)b * TT + t) * HH + hh0) = acc[i][j];
    }
  }
}

// ---------------- K6: ze = tanh(h @ outp_W^T + outp_b) ----------------
__global__ __launch_bounds__(256) void k_ze(
    const float* __restrict__ h, const float* __restrict__ outpW,
    const float* __restrict__ outpb, float* __restrict__ ze, int br0) {
  __shared__ __align__(16) float As[16][132];
  __shared__ __align__(16) float Ws[16][36];
  __shared__ __align__(16) float Cs[128][36];
  const int tid = threadIdx.x;
  const int b  = blockIdx.y;
  const int t0 = blockIdx.x * 128;
  const int br = br0 + (b >> 5);
  const float* W = outpW + (size_t)br * EE * HH;
  float acc[4][4] = {};
  const int ti = tid & 31, ni = tid >> 5;
  for (int k0 = 0; k0 < HH; k0 += 16) {
    __syncthreads();
    {
      int i = tid >> 1, kq = (tid & 1) * 8;
      const float* src = h + ((size_t)b * TT + t0 + i) * HH + k0 + kq;
      float4 a0 = *(const float4*)src;
      float4 a1 = *(const float4*)(src + 4);
      As[kq+0][i]=a0.x; As[kq+1][i]=a0.y; As[kq+2][i]=a0.z; As[kq+3][i]=a0.w;
      As[kq+4][i]=a1.x; As[kq+5][i]=a1.y; As[kq+6][i]=a1.z; As[kq+7][i]=a1.w;
    }
    for (int idx = tid; idx < 512; idx += 256) {
      int jj = idx >> 4, kk = idx & 15;
      Ws[kk][jj] = W[(size_t)jj * HH + k0 + kk];
    }
    __syncthreads();
    #pragma unroll
    for (int kk = 0; kk < 16; ++kk) {
      float4 a = *(const float4*)&As[kk][ti * 4];
      float4 w = *(const float4*)&Ws[kk][ni * 4];
      acc[0][0] += a.x*w.x; acc[0][1] += a.x*w.y; acc[0][2] += a.x*w.z; acc[0][3] += a.x*w.w;
      acc[1][0] += a.y*w.x; acc[1][1] += a.y*w.y; acc[1][2] += a.y*w.z; acc[1][3] += a.y*w.w;
      acc[2][0] += a.z*w.x; acc[2][1] += a.z*w.y; acc[2][2] += a.z*w.z; acc[2][3] += a.z*w.w;
      acc[3][0] += a.w*w.x; acc[3][1] += a.w*w.y; acc[3][2] += a.w*w.z; acc[3][3] += a.w*w.w;
    }
  }
  __syncthreads();
  float bj[4];
  #pragma unroll
  for (int c = 0; c < 4; ++c) bj[c] = outpb[br * EE + ni*4 + c];
  #pragma unroll
  for (int r = 0; r < 4; ++r)
    #pragma unroll
    for (int c = 0; c < 4; ++c)
      Cs[ti*4+r][ni*4+c] = tanhf(acc[r][c] + bj[c]);
  __syncthreads();
  int i = tid >> 1, j16 = (tid & 1) * 16;
  float* dst = ze + (((size_t)(br0 * 32 + b)) * TT + t0 + i) * EE + j16;
  #pragma unroll
  for (int q = 0; q < 4; ++q)
    *(float4*)(dst + q*4) = *(float4*)&Cs[i][j16 + q*4];
}

// ---------------- K7: hyperbolic combine ----------------
__device__ __forceinline__ void mobius_add32(const float* x, const float* y, float* o) {
  float x2 = 0.f, y2 = 0.f, xy = 0.f;
  #pragma unroll
  for (int i = 0; i < 32; ++i) { x2 += x[i]*x[i]; y2 += y[i]*y[i]; xy += x[i]*y[i]; }
  float ca  = 1.f + 2.f*xy + y2;
  float cb  = 1.f - x2;
  float den = 1.f + 2.f*xy + x2*y2;
  float inv = 1.f / fmaxf(den, 1e-15f);
  #pragma unroll
  for (int i = 0; i < 32; ++i) o[i] = (ca*x[i] + cb*y[i]) * inv;
}

__global__ __launch_bounds__(256) void k_hyper(const float* __restrict__ ze,
                                               float* __restrict__ out) {
  int idx = blockIdx.x * 256 + threadIdx.x;
  int b = idx >> 10, t = idx & 1023;
  float v[4][32];
  #pragma unroll
  for (int br = 0; br < 4; ++br) {
    const float* p = ze + (((size_t)br * BB + b) * TT + t) * EE;
    float s = 0.f;
    #pragma unroll
    for (int e = 0; e < 32; ++e) { v[br][e] = p[e]; s += v[br][e]*v[br][e]; }
    float nr = sqrtf(fmaxf(s, 1e-15f));
    float sc = tanhf(nr) / nr;
    float s2 = 0.f;
    #pragma unroll
    for (int e = 0; e < 32; ++e) { v[br][e] *= sc; s2 += v[br][e]*v[br][e]; }
    float n2 = sqrtf(fmaxf(s2, 1e-15f));
    if (n2 > 0.996f) {
      float sc2 = 0.996f / n2;
      #pragma unroll
      for (int e = 0; e < 32; ++e) v[br][e] *= sc2;
    }
    float* o = out + (((size_t)br * BB + b) * TT + t) * EE;
    #pragma unroll
    for (int e = 0; e < 32; ++e) o[e] = v[br][e];
  }
  float m1[32], m2[32];
  mobius_add32(v[1], v[2], m1);
  mobius_add32(v[0], m1, m2);
  mobius_add32(m2, v[3], m1);
  float s = 0.f;
  #pragma unroll
  for (int e = 0; e < 32; ++e) s += m1[e]*m1[e];
  float n = sqrtf(fmaxf(s, 1e-15f));
  if (n > 0.996f) {
    float sc = 0.996f / n;
    #pragma unroll
    for (int e = 0; e < 32; ++e) m1[e] *= sc;
  }
  float* o = out + (((size_t)4 * BB + b) * TT + t) * EE;
  #pragma unroll
  for (int e = 0; e < 32; ++e) o[e] = m1[e];
}

// ---------------- host ----------------
extern "C" void kernel_launch(void* const* d_in, const int* in_sizes, int n_in,
                              void* d_out, int out_size, void* d_ws, size_t ws_size,
                              hipStream_t stream) {
  const float* xs0 = (const float*)d_in[0];
  const float* xs1 = (const float*)d_in[1];
  const float* xs2 = (const float*)d_in[2];
  const float* xs3 = (const float*)d_in[3];
  const float* inpW   = (const float*)d_in[4];
  const float* inpb   = (const float*)d_in[5];
  const float* iprojW = (const float*)d_in[6];
  const float* convW  = (const float*)d_in[7];
  const float* convb  = (const float*)d_in[8];
  const float* xprojW = (const float*)d_in[9];
  const float* dtW    = (const float*)d_in[10];
  const float* dtb    = (const float*)d_in[11];
  const float* A_log  = (const float*)d_in[12];
  const float* D_skip = (const float*)d_in[13];
  const float* outW   = (const float*)d_in[14];
  const float* outpW  = (const float*)d_in[15];
  const float* outpb  = (const float*)d_in[16];
  float* out = (float*)d_out;

  // pre-split weight buffers at the head of ws (ushort)
  const size_t wUshorts = 2 * (WXZ_N + WXD_N + WOUT_N);
  ushort* WxzH = (ushort*)d_ws;
  ushort* WxzL = WxzH + WXZ_N;
  ushort* WxdH = WxzL + WXZ_N;
  ushort* WxdL = WxdH + WXD_N;
  ushort* WoH  = WxdL + WXD_N;
  ushort* WoL  = WoH + WOUT_N;
  float* ws = (float*)(WoL + WOUT_N);

  const size_t zeF = (size_t)4 * BB * TT * EE;
  // per fused batch row: h 65536 (Hloc aliases its lower half) +
  // xr/zb/g/cd 4*131072 + Cm 16384 + sdt 2048
  const size_t perBl = 65536 + 4 * 131072 + 16384 + 2048;
  auto needBytes = [&](int NB) {
    return (zeF + (size_t)NB * 32 * perBl) * 4 + wUshorts * 2;
  };
  int NB = 4;
  if (needBytes(4) > ws_size) NB = 2;
  if (NB == 2 && needBytes(2) > ws_size) NB = 1;
  const int nbl = NB * 32;

  float* ze = ws;
  float* h  = ze + zeF;
  float* xr = h  + (size_t)nbl * 65536;
  float* zb = xr + (size_t)nbl * 131072;
  float* g  = zb + (size_t)nbl * 131072;   // y buffer
  float* cd = g  + (size_t)nbl * 131072;   // per-chunk dt-cumsum
  float* Cm = cd + (size_t)nbl * 131072;
  float* sdt = Cm + (size_t)nbl * 16384;
  float* Hloc = h;  // alias: Hloc dead before k_out writes h (r8+ structure)

  k_presplit<<<WXZ_N / 256, 256, 0, stream>>>(iprojW, xprojW, outW,
                                              WxzH, WxzL, WxdH, WxdL, WoH, WoL);

  for (int br0 = 0; br0 < 4; br0 += NB) {
    k_xz<<<dim3(16, nbl), 256, 0, stream>>>(xs0, xs1, xs2, xs3,
                                            WxzH, WxzL, inpW, inpb, xr, zb, br0);
    for (int l = 0; l < LL; ++l) {
      k_xds<<<dim3(16, nbl), 512, 0, stream>>>(xr, convW, convb, WxdH, WxdL,
                                               dtW, dtb, A_log, D_skip,
                                               cd, Cm, Hloc, g, sdt, br0, l);
      k_scan2<<<nbl * 60, 256, 0, stream>>>(cd, Cm, A_log, Hloc, sdt, g, br0, l);
      if (l < LL - 1)
        k_outxz<<<dim3(16, nbl), 256, 0, stream>>>(g, zb, WoH, WoL, WxzH, WxzL,
                                                   xr, br0, l);
      else
        k_out<<<dim3(16, nbl), 256, 0, stream>>>(g, zb, WoH, WoL, h, br0, l);
    }
    k_ze<<<dim3(8, nbl), 256, 0, stream>>>(h, outpW, outpb, ze, br0);
  }
  k_hyper<<<BB * TT / 256, 256, 0, stream>>>(ze, out);
}

// Round 15
// 933.946 us; speedup vs baseline: 1.0424x; 1.0424x over previous
//
#include <hip/hip_runtime.h>
#include <math.h>

#define TT 1024
#define DIN 128
#define HH 64
#define NN 16
#define EE 32
#define LL 3
#define BB 32
#define LOG2E 1.4426950408889634f

__device__ __forceinline__ float siluf(float x) { return x / (1.f + __expf(-x)); }
// raw v_exp_f32 (2^x) -- __exp2f does not exist in HIP device code
__device__ __forceinline__ float exp2fast(float x) { return __builtin_amdgcn_exp2f(x); }

typedef __attribute__((ext_vector_type(8))) short bf16x8;
typedef __attribute__((ext_vector_type(4))) float f32x4;

// split fp32 into bf16 hi + bf16 lo (truncation; a ~= hi + lo, err ~2^-16 rel)
__device__ __forceinline__ void split2(float x, ushort& hi, ushort& lo) {
  unsigned u = __float_as_uint(x);
  hi = (ushort)(u >> 16);
  float rem = x - __uint_as_float((u >> 16) << 16);
  lo = (ushort)(__float_as_uint(rem) >> 16);
}

// pre-split weight buffer sizes (ushort counts)
#define WXZ_N 196608  // 4*3*256*64
#define WXD_N 73728   // 4*3*48*128 (n padded 36->48 with zeros)
#define WOUT_N 98304  // 4*3*64*128

// ---------------- K0: one-shot pre-split of all MFMA weights ----------------
__global__ __launch_bounds__(256) void k_presplit(
    const float* __restrict__ iprojW, const float* __restrict__ xprojW,
    const float* __restrict__ outW,
    ushort* __restrict__ WxzH, ushort* __restrict__ WxzL,
    ushort* __restrict__ WxdH, ushort* __restrict__ WxdL,
    ushort* __restrict__ WoH, ushort* __restrict__ WoL) {
  int idx = blockIdx.x * 256 + threadIdx.x;
  if (idx < WXZ_N) {
    ushort h, l;
    split2(iprojW[idx], h, l);
    WxzH[idx] = h; WxzL[idx] = l;
  }
  if (idx < WXD_N) {
    int k = idx & 127, r = (idx >> 7) % 48, bl = idx / (48 * 128);
    float v = (r < 36) ? xprojW[((size_t)(bl * 36 + r)) * 128 + k] : 0.f;
    ushort h, l;
    split2(v, h, l);
    WxdH[idx] = h; WxdL[idx] = l;
  }
  if (idx < WOUT_N) {
    ushort h, l;
    split2(outW[idx], h, l);
    WoH[idx] = h; WoL[idx] = l;
  }
}

// ---------------- K1: xz = h @ inW^T via split-bf16 MFMA (l==0 only) ----------------
__global__ __launch_bounds__(256) void k_xz(
    const float* __restrict__ x0, const float* __restrict__ x1,
    const float* __restrict__ x2, const float* __restrict__ x3,
    const ushort* __restrict__ WH, const ushort* __restrict__ WL,
    const float* __restrict__ inpW, const float* __restrict__ inpb,
    float* __restrict__ xr, float* __restrict__ zb, int br0) {
  __shared__ __align__(16) ushort Hh[64][72], Hl[64][72];  // h tile [t][k]
  const int tid = threadIdx.x;
  const int b  = blockIdx.y;
  const int t0 = blockIdx.x * 64;
  const int br = br0 + (b >> 5);
  {
    const int row = tid >> 2, c0 = (tid & 3) * 16;
    int bb = b & 31;
    const float* xp = (br == 0) ? x0 : (br == 1) ? x1 : (br == 2) ? x2 : x3;
    float xv = xp[bb * TT + t0 + row];
    #pragma unroll
    for (int q = 0; q < 4; ++q) {
      float4 w4 = *(const float4*)(inpW + br * HH + c0 + q * 4);
      float4 b4 = *(const float4*)(inpb + br * HH + c0 + q * 4);
      float4 hv;
      hv.x = xv * w4.x + b4.x; hv.y = xv * w4.y + b4.y;
      hv.z = xv * w4.z + b4.z; hv.w = xv * w4.w + b4.w;
      ushort h0,h1,h2,h3,l0,l1,l2,l3;
      split2(hv.x,h0,l0); split2(hv.y,h1,l1); split2(hv.z,h2,l2); split2(hv.w,h3,l3);
      *(ushort4*)&Hh[row][c0 + q*4] = make_ushort4(h0,h1,h2,h3);
      *(ushort4*)&Hl[row][c0 + q*4] = make_ushort4(l0,l1,l2,l3);
    }
  }
  __syncthreads();
  const int wave = tid >> 6, lane = tid & 63;
  const int quad = lane >> 4, l16 = lane & 15;
  const int nsub = (wave & 1) * 32, tsub = (wave >> 1) * 32;
  const size_t wbase = (size_t)(br * LL) * 256;
  for (int n0 = 0; n0 < 2 * DIN; n0 += 64) {
    f32x4 acc[2][2] = {};   // [n-frag][t-frag]
    #pragma unroll
    for (int k0 = 0; k0 < 64; k0 += 32) {
      bf16x8 Ah[2], Al[2], Bh[2], Bl[2];
      #pragma unroll
      for (int i = 0; i < 2; ++i) {
        size_t ro = (wbase + n0 + nsub + i * 16 + l16) * 64 + k0 + quad * 8;
        Ah[i] = *(const bf16x8*)(WH + ro);
        Al[i] = *(const bf16x8*)(WL + ro);
        Bh[i] = *(const bf16x8*)&Hh[tsub + i*16 + l16][k0 + quad*8];
        Bl[i] = *(const bf16x8*)&Hl[tsub + i*16 + l16][k0 + quad*8];
      }
      #pragma unroll
      for (int i = 0; i < 2; ++i)
        #pragma unroll
        for (int j = 0; j < 2; ++j) {
          acc[i][j] = __builtin_amdgcn_mfma_f32_16x16x32_bf16(Ah[i], Bh[j], acc[i][j], 0, 0, 0);
          acc[i][j] = __builtin_amdgcn_mfma_f32_16x16x32_bf16(Ah[i], Bl[j], acc[i][j], 0, 0, 0);
          acc[i][j] = __builtin_amdgcn_mfma_f32_16x16x32_bf16(Al[i], Bh[j], acc[i][j], 0, 0, 0);
        }
    }
    // D layout: col(t) = lane&15, row(n) = quad*4 + reg
    #pragma unroll
    for (int i = 0; i < 2; ++i) {
      #pragma unroll
      for (int r = 0; r < 4; ++r) {
        int n = n0 + nsub + i*16 + quad*4 + r;
        float* dst = (n < DIN) ? (xr + ((size_t)b * DIN + n) * TT)
                               : (zb + ((size_t)b * DIN + (n - DIN)) * TT);
        #pragma unroll
        for (int j = 0; j < 2; ++j)
          dst[t0 + tsub + j*16 + l16] = acc[i][j][r];
      }
    }
  }
}

// ---- K3: FUSED conv+silu + x_dbl GEMM + local chunk scan ----
// r15 = r13 verbatim (measured best: 74.9us, 56% VALU, no spill). r14's
// 512-thread variant regressed (+8us: 4x softplus duplication + 2x U-split).
__global__ __launch_bounds__(256) void k_xds(
    const float* __restrict__ xr, const float* __restrict__ convW,
    const float* __restrict__ convb, const ushort* __restrict__ WH,
    const ushort* __restrict__ WL, const float* __restrict__ dtW,
    const float* __restrict__ dtb, const float* __restrict__ A_log,
    const float* __restrict__ D_skip,
    float* __restrict__ cd, float* __restrict__ Cm,
    float* __restrict__ Hloc, float* __restrict__ g, float* __restrict__ sdt,
    int br0, int l) {
  __shared__ __align__(16) float U[128][66];   // u tile fp32 [d][t]; stride 66
  __shared__ __align__(16) float Xs[36][68];   // x_dbl: 0..3 dt_r, 4..19 B, 20..35 C
  const int tid = threadIdx.x;
  const int b  = blockIdx.y;
  const int c  = blockIdx.x;           // chunk index
  const int t0 = c * 64;
  const int br = br0 + (b >> 5);
  const int wave = tid >> 6, lane = tid & 63;
  const int quad = lane >> 4, l16 = lane & 15;
  const int tw = wave * 16;            // wave's t-offset
  const size_t wb48 = (size_t)(br * LL + l) * 48 * 128;
  const int dd = tid >> 1, p = tid & 1;
  // ---- conv+silu: global->regs->U, no LDS staging, no inner barriers ----
  {
    const int tb = t0 + p * 32;                      // window start for this half
    const float* src = xr + ((size_t)b * DIN + dd) * TT + tb;
    float r[36];                                     // x[tb-4 .. tb+31]
    #pragma unroll
    for (int q = 0; q < 9; ++q) {
      float4 f = make_float4(0.f, 0.f, 0.f, 0.f);
      if (q > 0 || tb > 0) f = *(const float4*)(src - 4 + q * 4);
      r[q*4+0] = f.x; r[q*4+1] = f.y; r[q*4+2] = f.z; r[q*4+3] = f.w;
    }
    const int wb0 = (br * LL + l) * DIN + dd;
    const float* w = convW + (size_t)wb0 * 4;
    const float w0 = w[0], w1 = w[1], w2 = w[2], w3 = w[3];
    const float cb = convb[wb0];
    #pragma unroll
    for (int i = 0; i < 32; i += 2) {
      float o0 = siluf(r[i+1]*w0 + r[i+2]*w1 + r[i+3]*w2 + r[i+4]*w3 + cb);
      float o1 = siluf(r[i+2]*w0 + r[i+3]*w1 + r[i+4]*w2 + r[i+5]*w3 + cb);
      *(float2*)&U[dd][p * 32 + i] = make_float2(o0, o1);
    }
  }
  __syncthreads();   // barrier 1: U complete
  // ---- GEMM: x_dbl = W @ u, barrier-free (U is read-only from here) ----
  f32x4 acc[3] = {};                   // 3 n-frags (n = 0..47), t = tw..tw+15
  #pragma unroll
  for (int k0 = 0; k0 < DIN; k0 += 32) {
    ushort bh[8], bl[8];
    #pragma unroll
    for (int j = 0; j < 8; ++j)
      split2(U[k0 + quad * 8 + j][tw + l16], bh[j], bl[j]);
    bf16x8 Bh = *(bf16x8*)bh, Bl = *(bf16x8*)bl;
    #pragma unroll
    for (int nf = 0; nf < 3; ++nf) {
      size_t ro = wb48 + (size_t)(nf * 16 + l16) * 128 + k0 + quad * 8;
      bf16x8 Whf = *(const bf16x8*)(WH + ro);
      bf16x8 Wlf = *(const bf16x8*)(WL + ro);
      acc[nf] = __builtin_amdgcn_mfma_f32_16x16x32_bf16(Whf, Bh, acc[nf], 0, 0, 0);
      acc[nf] = __builtin_amdgcn_mfma_f32_16x16x32_bf16(Whf, Bl, acc[nf], 0, 0, 0);
      acc[nf] = __builtin_amdgcn_mfma_f32_16x16x32_bf16(Wlf, Bh, acc[nf], 0, 0, 0);
    }
  }
  // D layout: col(t) = l16, row(n) = quad*4 + r  ->  Xs[n][t]
  #pragma unroll
  for (int nf = 0; nf < 3; ++nf) {
    #pragma unroll
    for (int r = 0; r < 4; ++r) {
      int n = nf * 16 + quad * 4 + r;
      if (n < 36) Xs[n][tw + l16] = acc[nf][r];
    }
  }
  __syncthreads();   // barrier 2: Xs complete
  // Cm needed globally (k_scan2 stages it)
  {
    int n = tid >> 4, i0 = (tid & 15) * 4;
    *(float4*)(Cm + ((size_t)b * NN + n) * TT + t0 + i0) = *(float4*)&Xs[20 + n][i0];
  }
  // ---------------- scan phase: 2 threads per d, 8 n-states each ----------------
  const int n0s = p * 8;
  const int wbase = (br * LL + l) * DIN + dd;
  const float* wd = dtW + (size_t)wbase * 4;
  const float w0 = wd[0], w1 = wd[1], w2 = wd[2], w3 = wd[3];
  const float bias = dtb[wbase];
  float Ac[8];   // pre-scaled by log2e: exp(dt*A) == exp2(dt*Ac)
  #pragma unroll
  for (int j = 0; j < 8; ++j)
    Ac[j] = -LOG2E * __expf(A_log[(size_t)wbase * NN + n0s + j]);
  const float Dp = D_skip[wbase];
  float hst[8] = {0.f,0.f,0.f,0.f,0.f,0.f,0.f,0.f};
  float sd = 0.f;
  float* gp  = g  + ((size_t)b * DIN + dd) * TT + t0;
  float* cdp = cd + ((size_t)b * DIN + dd) * TT + t0;
  for (int t8 = 0; t8 < 64; t8 += 8) {
    // dt-source rows (broadcast reads; all lanes same address)
    float4 a0 = *(const float4*)&Xs[0][t8], a0b = *(const float4*)&Xs[0][t8 + 4];
    float4 a1 = *(const float4*)&Xs[1][t8], a1b = *(const float4*)&Xs[1][t8 + 4];
    float4 a2 = *(const float4*)&Xs[2][t8], a2b = *(const float4*)&Xs[2][t8 + 4];
    float4 a3 = *(const float4*)&Xs[3][t8], a3b = *(const float4*)&Xs[3][t8 + 4];
    float x0v[8] = {a0.x,a0.y,a0.z,a0.w,a0b.x,a0b.y,a0b.z,a0b.w};
    float x1v[8] = {a1.x,a1.y,a1.z,a1.w,a1b.x,a1b.y,a1b.z,a1b.w};
    float x2v[8] = {a2.x,a2.y,a2.z,a2.w,a2b.x,a2b.y,a2b.z,a2b.w};
    float x3v[8] = {a3.x,a3.y,a3.z,a3.w,a3b.x,a3b.y,a3b.z,a3b.w};
    float us[8];
    {
      float2 u0 = *(const float2*)&U[dd][t8];
      float2 u1 = *(const float2*)&U[dd][t8 + 2];
      float2 u2 = *(const float2*)&U[dd][t8 + 4];
      float2 u3 = *(const float2*)&U[dd][t8 + 6];
      us[0]=u0.x; us[1]=u0.y; us[2]=u1.x; us[3]=u1.y;
      us[4]=u2.x; us[5]=u2.y; us[6]=u3.x; us[7]=u3.y;
    }
    float dts[8], cds[8], du[8];
    #pragma unroll
    for (int s = 0; s < 8; ++s) {
      float sv = x0v[s]*w0 + x1v[s]*w1 + x2v[s]*w2 + x3v[s]*w3 + bias;
      float e = __expf(-fabsf(sv));
      float dtv = fmaxf(sv, 0.f) + __logf(1.f + e);   // softplus, same as before
      sd += dtv;
      dts[s] = dtv;
      cds[s] = sd;
      du[s] = dtv * us[s];
    }
    float acc8[8] = {0.f,0.f,0.f,0.f,0.f,0.f,0.f,0.f};
    #pragma unroll
    for (int j = 0; j < 8; ++j) {
      int n = n0s + j;
      float4 bq0 = *(const float4*)&Xs[4 + n][t8];
      float4 bq1 = *(const float4*)&Xs[4 + n][t8 + 4];
      float4 cq0 = *(const float4*)&Xs[20 + n][t8];
      float4 cq1 = *(const float4*)&Xs[20 + n][t8 + 4];
      float Bv[8] = {bq0.x,bq0.y,bq0.z,bq0.w,bq1.x,bq1.y,bq1.z,bq1.w};
      float Cv[8] = {cq0.x,cq0.y,cq0.z,cq0.w,cq1.x,cq1.y,cq1.z,cq1.w};
      float hj = hst[j], an = Ac[j];
      #pragma unroll
      for (int s = 0; s < 8; ++s) {
        hj = exp2fast(dts[s] * an) * hj + du[s] * Bv[s];
        acc8[s] += hj * Cv[s];
      }
      hst[j] = hj;
    }
    #pragma unroll
    for (int s = 0; s < 8; ++s) {
      float tot = acc8[s] + __shfl_xor(acc8[s], 1, 2);  // pair: n 0..7 + n 8..15
      acc8[s] = tot + Dp * us[s];
    }
    if (p == 0) {
      *(float4*)(gp + t8)      = make_float4(acc8[0], acc8[1], acc8[2], acc8[3]);
      *(float4*)(gp + t8 + 4)  = make_float4(acc8[4], acc8[5], acc8[6], acc8[7]);
      *(float4*)(cdp + t8)     = make_float4(cds[0], cds[1], cds[2], cds[3]);
      *(float4*)(cdp + t8 + 4) = make_float4(cds[4], cds[5], cds[6], cds[7]);
    }
  }
  {
    float* hp = Hloc + (((size_t)b * DIN + dd) * 16 + c) * 16 + n0s;
    *(float4*)hp       = make_float4(hst[0], hst[1], hst[2], hst[3]);
    *(float4*)(hp + 4) = make_float4(hst[4], hst[5], hst[6], hst[7]);
  }
  if (p == 0) sdt[((size_t)b * DIN + dd) * 16 + c] = sd;
}

// ---- K4c: combine (from Hloc + sdt) + parallel correction; reads precomputed cd ----
__global__ __launch_bounds__(256) void k_scan2(
    const float* __restrict__ cdc, const float* __restrict__ Cm,
    const float* __restrict__ A_log, const float* __restrict__ Hloc,
    const float* __restrict__ sdt, float* __restrict__ g, int br0, int l) {
  __shared__ __align__(16) float Cl[16][68];
  __shared__ __align__(16) float HinL[32][16];
  const int bx  = blockIdx.x;
  const int b   = bx / 60;
  const int rem = bx % 60;
  const int c   = (rem >> 2) + 1;   // 1..15
  const int dq  = rem & 3;
  const int tid = threadIdx.x;
  const int br  = br0 + (b >> 5);
  {
    int row = tid >> 4, cc = (tid & 15) * 4;
    *(float4*)&Cl[row][cc] = *(const float4*)(Cm + ((size_t)b * NN + row) * TT + c * 64 + cc);
  }
  const int dloc = tid >> 3, tg = tid & 7;
  const int d  = dq * 32 + dloc;
  size_t off = ((size_t)b * DIN + d) * TT + c * 64 + tg * 8;
  float* gp = g + off;
  float4 y0 = *(const float4*)gp;
  float4 y1 = *(const float4*)(gp + 4);
  float4 cq0 = *(const float4*)(cdc + off);
  float4 cq1 = *(const float4*)(cdc + off + 4);
  {
    int n0 = (tid & 7) * 2;
    int wbase = (br * LL + l) * DIN + d;
    float a0 = -LOG2E * __expf(A_log[(size_t)wbase * NN + n0]);
    float a1 = -LOG2E * __expf(A_log[(size_t)wbase * NN + n0 + 1]);
    float h0 = 0.f, h1 = 0.f;
    const float* sp  = sdt + ((size_t)b * DIN + d) * 16;
    const float* hlb = Hloc + ((size_t)b * DIN + d) * 256;
    for (int cc = 0; cc < c; ++cc) {
      float sdv = sp[cc];
      float2 hl = *(const float2*)(hlb + cc * 16 + n0);
      h0 = exp2fast(a0 * sdv) * h0 + hl.x;
      h1 = exp2fast(a1 * sdv) * h1 + hl.y;
    }
    HinL[dloc][n0] = h0;
    HinL[dloc][n0 + 1] = h1;
  }
  __syncthreads();
  float cd8[8] = {cq0.x, cq0.y, cq0.z, cq0.w, cq1.x, cq1.y, cq1.z, cq1.w};
  const float* al = A_log + (size_t)((br * LL + l) * DIN + d) * NN;
  float Ac16[16];
  #pragma unroll
  for (int n = 0; n < 16; ++n) Ac16[n] = -LOG2E * __expf(al[n]);
  float y8[8] = {y0.x, y0.y, y0.z, y0.w, y1.x, y1.y, y1.z, y1.w};
  const int tbase = tg * 8;
  #pragma unroll
  for (int n = 0; n < 16; ++n) {
    float hv = HinL[dloc][n];
    float an = Ac16[n];
    #pragma unroll
    for (int s = 0; s < 8; ++s)
      y8[s] += Cl[n][tbase + s] * exp2fast(an * cd8[s]) * hv;
  }
  *(float4*)gp       = make_float4(y8[0], y8[1], y8[2], y8[3]);
  *(float4*)(gp + 4) = make_float4(y8[4], y8[5], y8[6], y8[7]);
}

// ---- K5b: FUSED k_out(l) + k_xz(l+1) ----
__global__ __launch_bounds__(256) void k_outxz(
    const float* __restrict__ graw, float* zb,
    const ushort* __restrict__ WoHp, const ushort* __restrict__ WoLp,
    const ushort* __restrict__ WxHp, const ushort* __restrict__ WxLp,
    float* __restrict__ xr, int br0, int l) {
  __shared__ __align__(16) ushort Bh_[64][72], Bl_[64][72];
  const int tid = threadIdx.x;
  const int b  = blockIdx.y;
  const int t0 = blockIdx.x * 64;
  const int br = br0 + (b >> 5);
  const int wave = tid >> 6, lane = tid & 63;
  const int quad = lane >> 4, l16 = lane & 15;
  const int hsub = (wave & 1) * 32, tsub = (wave >> 1) * 32;
  const size_t wbo = (size_t)(br * LL + l) * 64;
  // ---- GEMM1: h-tile = (y*silu(z)) @ outW^T (registers only) ----
  f32x4 acc[2][2] = {};   // [hh-frag][t-frag]
  for (int k0 = 0; k0 < DIN; k0 += 64) {
    __syncthreads();
    {
      int row = tid >> 2, c0 = (tid & 3) * 16;
      #pragma unroll
      for (int q = 0; q < 4; ++q) {
        size_t off = ((size_t)b * DIN + k0 + row) * TT + t0 + c0 + q * 4;
        float4 gv = *(const float4*)(graw + off);
        float4 zv = *(const float4*)(zb + off);
        float a0 = gv.x * siluf(zv.x), a1 = gv.y * siluf(zv.y);
        float a2 = gv.z * siluf(zv.z), a3 = gv.w * siluf(zv.w);
        ushort h0,h1,h2,h3,l0,l1,l2,l3;
        split2(a0,h0,l0); split2(a1,h1,l1); split2(a2,h2,l2); split2(a3,h3,l3);
        *(ushort4*)&Bh_[row][c0 + q*4] = make_ushort4(h0,h1,h2,h3);
        *(ushort4*)&Bl_[row][c0 + q*4] = make_ushort4(l0,l1,l2,l3);
      }
    }
    __syncthreads();
    #pragma unroll
    for (int kk = 0; kk < 64; kk += 32) {
      bf16x8 Ahf[2], Alf[2], Bhf[2], Blf[2];
      #pragma unroll
      for (int i = 0; i < 2; ++i) {
        size_t ro = (wbo + hsub + i * 16 + l16) * 128 + k0 + kk + quad * 8;
        Ahf[i] = *(const bf16x8*)(WoHp + ro);
        Alf[i] = *(const bf16x8*)(WoLp + ro);
        Bhf[i] = *(const bf16x8*)&Bh_[tsub + i*16 + l16][kk + quad*8];
        Blf[i] = *(const bf16x8*)&Bl_[tsub + i*16 + l16][kk + quad*8];
      }
      #pragma unroll
      for (int i = 0; i < 2; ++i)
        #pragma unroll
        for (int j = 0; j < 2; ++j) {
          acc[i][j] = __builtin_amdgcn_mfma_f32_16x16x32_bf16(Ahf[i], Bhf[j], acc[i][j], 0, 0, 0);
          acc[i][j] = __builtin_amdgcn_mfma_f32_16x16x32_bf16(Ahf[i], Blf[j], acc[i][j], 0, 0, 0);
          acc[i][j] = __builtin_amdgcn_mfma_f32_16x16x32_bf16(Alf[i], Bhf[j], acc[i][j], 0, 0, 0);
        }
    }
  }
  __syncthreads();   // all GEMM1 LDS reads complete -> Bh_/Bl_ reusable
  // ---- write h tile (bf16 split) into Bh_/Bl_ as Hh[t][hh] ----
  #pragma unroll
  for (int i = 0; i < 2; ++i) {
    int hh0 = hsub + i*16 + quad*4;
    #pragma unroll
    for (int j = 0; j < 2; ++j) {
      int t = tsub + j*16 + l16;
      ushort h0,h1,h2,h3,l0,l1,l2,l3;
      split2(acc[i][j][0],h0,l0); split2(acc[i][j][1],h1,l1);
      split2(acc[i][j][2],h2,l2); split2(acc[i][j][3],h3,l3);
      *(ushort2*)&Bh_[t][hh0]     = make_ushort2(h0,h1);
      *(ushort2*)&Bh_[t][hh0 + 2] = make_ushort2(h2,h3);
      *(ushort2*)&Bl_[t][hh0]     = make_ushort2(l0,l1);
      *(ushort2*)&Bl_[t][hh0 + 2] = make_ushort2(l2,l3);
    }
  }
  __syncthreads();
  // ---- GEMM2: xz(l+1) = h @ inprojW(l+1)^T ----
  const size_t wbase = (size_t)(br * LL + (l + 1)) * 256;
  const int nsub = hsub;
  for (int n0 = 0; n0 < 2 * DIN; n0 += 64) {
    f32x4 a2[2][2] = {};
    #pragma unroll
    for (int k0 = 0; k0 < 64; k0 += 32) {
      bf16x8 Ah[2], Al[2], Bh[2], Bl[2];
      #pragma unroll
      for (int i = 0; i < 2; ++i) {
        size_t ro = (wbase + n0 + nsub + i * 16 + l16) * 64 + k0 + quad * 8;
        Ah[i] = *(const bf16x8*)(WxHp + ro);
        Al[i] = *(const bf16x8*)(WxLp + ro);
        Bh[i] = *(const bf16x8*)&Bh_[tsub + i*16 + l16][k0 + quad*8];
        Bl[i] = *(const bf16x8*)&Bl_[tsub + i*16 + l16][k0 + quad*8];
      }
      #pragma unroll
      for (int i = 0; i < 2; ++i)
        #pragma unroll
        for (int j = 0; j < 2; ++j) {
          a2[i][j] = __builtin_amdgcn_mfma_f32_16x16x32_bf16(Ah[i], Bh[j], a2[i][j], 0, 0, 0);
          a2[i][j] = __builtin_amdgcn_mfma_f32_16x16x32_bf16(Ah[i], Bl[j], a2[i][j], 0, 0, 0);
          a2[i][j] = __builtin_amdgcn_mfma_f32_16x16x32_bf16(Al[i], Bh[j], a2[i][j], 0, 0, 0);
        }
    }
    #pragma unroll
    for (int i = 0; i < 2; ++i) {
      #pragma unroll
      for (int r = 0; r < 4; ++r) {
        int n = n0 + nsub + i*16 + quad*4 + r;
        float* dst = (n < DIN) ? (xr + ((size_t)b * DIN + n) * TT)
                               : (zb + ((size_t)b * DIN + (n - DIN)) * TT);
        #pragma unroll
        for (int j = 0; j < 2; ++j)
          dst[t0 + tsub + j*16 + l16] = a2[i][j][r];
      }
    }
  }
}

// ---------------- K5: h = (y * silu(z)) @ outW^T (l==2 only) ----------------
__global__ __launch_bounds__(256) void k_out(
    const float* __restrict__ graw, const float* __restrict__ zb,
    const ushort* __restrict__ WH, const ushort* __restrict__ WL,
    float* __restrict__ h, int br0, int l) {
  __shared__ __align__(16) ushort Bh_[64][72], Bl_[64][72];  // act tile [d][t]
  const int tid = threadIdx.x;
  const int b  = blockIdx.y;
  const int t0 = blockIdx.x * 64;
  const int br = br0 + (b >> 5);
  const int wave = tid >> 6, lane = tid & 63;
  const int quad = lane >> 4, l16 = lane & 15;
  const int hsub = (wave & 1) * 32, tsub = (wave >> 1) * 32;
  const size_t wb = (size_t)(br * LL + l) * 64;
  f32x4 acc[2][2] = {};   // [hh-frag][t-frag]
  for (int k0 = 0; k0 < DIN; k0 += 64) {
    __syncthreads();
    {
      int row = tid >> 2, c0 = (tid & 3) * 16;
      #pragma unroll
      for (int q = 0; q < 4; ++q) {
        size_t off = ((size_t)b * DIN + k0 + row) * TT + t0 + c0 + q * 4;
        float4 gv = *(const float4*)(graw + off);
        float4 zv = *(const float4*)(zb + off);
        float a0 = gv.x * siluf(zv.x), a1 = gv.y * siluf(zv.y);
        float a2 = gv.z * siluf(zv.z), a3 = gv.w * siluf(zv.w);
        ushort h0,h1,h2,h3,l0,l1,l2,l3;
        split2(a0,h0,l0); split2(a1,h1,l1); split2(a2,h2,l2); split2(a3,h3,l3);
        *(ushort4*)&Bh_[row][c0 + q*4] = make_ushort4(h0,h1,h2,h3);
        *(ushort4*)&Bl_[row][c0 + q*4] = make_ushort4(l0,l1,l2,l3);
      }
    }
    __syncthreads();
    #pragma unroll
    for (int kk = 0; kk < 64; kk += 32) {
      bf16x8 Ahf[2], Alf[2], Bhf[2], Blf[2];
      #pragma unroll
      for (int i = 0; i < 2; ++i) {
        size_t ro = (wb + hsub + i * 16 + l16) * 128 + k0 + kk + quad * 8;
        Ahf[i] = *(const bf16x8*)(WH + ro);
        Alf[i] = *(const bf16x8*)(WL + ro);
        Bhf[i] = *(const bf16x8*)&Bh_[tsub + i*16 + l16][kk + quad*8];
        Blf[i] = *(const bf16x8*)&Bl_[tsub + i*16 + l16][kk + quad*8];
      }
      #pragma unroll
      for (int i = 0; i < 2; ++i)
        #pragma unroll
        for (int j = 0; j < 2; ++j) {
          acc[i][j] = __builtin_amdgcn_mfma_f32_16x16x32_bf16(Ahf[i], Bhf[j], acc[i][j], 0, 0, 0);
          acc[i][j] = __builtin_amdgcn_mfma_f32_16x16x32_bf16(Ahf[i], Blf[j], acc[i][j], 0, 0, 0);
          acc[i][j] = __builtin_amdgcn_mfma_f32_16x16x32_bf16(Alf[i], Bhf[j], acc[i][j], 0, 0, 0);
        }
    }
  }
  #pragma unroll
  for (int i = 0; i < 2; ++i) {
    int hh0 = hsub + i*16 + quad*4;
    #pragma unroll
    for (int j = 0; j < 2; ++j) {
      int t = t0 + tsub + j*16 + l16;
      *(f32x4*)(h + ((size_t)b * TT + t) * HH + hh0) = acc[i][j];
    }
  }
}

// ---------------- K6: ze = tanh(h @ outp_W^T + outp_b) ----------------
__global__ __launch_bounds__(256) void k_ze(
    const float* __restrict__ h, const float* __restrict__ outpW,
    const float* __restrict__ outpb, float* __restrict__ ze, int br0) {
  __shared__ __align__(16) float As[16][132];
  __shared__ __align__(16) float Ws[16][36];
  __shared__ __align__(16) float Cs[128][36];
  const int tid = threadIdx.x;
  const int b  = blockIdx.y;
  const int t0 = blockIdx.x * 128;
  const int br = br0 + (b >> 5);
  const float* W = outpW + (size_t)br * EE * HH;
  float acc[4][4] = {};
  const int ti = tid & 31, ni = tid >> 5;
  for (int k0 = 0; k0 < HH; k0 += 16) {
    __syncthreads();
    {
      int i = tid >> 1, kq = (tid & 1) * 8;
      const float* src = h + ((size_t)b * TT + t0 + i) * HH + k0 + kq;
      float4 a0 = *(const float4*)src;
      float4 a1 = *(const float4*)(src + 4);
      As[kq+0][i]=a0.x; As[kq+1][i]=a0.y; As[kq+2][i]=a0.z; As[kq+3][i]=a0.w;
      As[kq+4][i]=a1.x; As[kq+5][i]=a1.y; As[kq+6][i]=a1.z; As[kq+7][i]=a1.w;
    }
    for (int idx = tid; idx < 512; idx += 256) {
      int jj = idx >> 4, kk = idx & 15;
      Ws[kk][jj] = W[(size_t)jj * HH + k0 + kk];
    }
    __syncthreads();
    #pragma unroll
    for (int kk = 0; kk < 16; ++kk) {
      float4 a = *(const float4*)&As[kk][ti * 4];
      float4 w = *(const float4*)&Ws[kk][ni * 4];
      acc[0][0] += a.x*w.x; acc[0][1] += a.x*w.y; acc[0][2] += a.x*w.z; acc[0][3] += a.x*w.w;
      acc[1][0] += a.y*w.x; acc[1][1] += a.y*w.y; acc[1][2] += a.y*w.z; acc[1][3] += a.y*w.w;
      acc[2][0] += a.z*w.x; acc[2][1] += a.z*w.y; acc[2][2] += a.z*w.z; acc[2][3] += a.z*w.w;
      acc[3][0] += a.w*w.x; acc[3][1] += a.w*w.y; acc[3][2] += a.w*w.z; acc[3][3] += a.w*w.w;
    }
  }
  __syncthreads();
  float bj[4];
  #pragma unroll
  for (int c = 0; c < 4; ++c) bj[c] = outpb[br * EE + ni*4 + c];
  #pragma unroll
  for (int r = 0; r < 4; ++r)
    #pragma unroll
    for (int c = 0; c < 4; ++c)
      Cs[ti*4+r][ni*4+c] = tanhf(acc[r][c] + bj[c]);
  __syncthreads();
  int i = tid >> 1, j16 = (tid & 1) * 16;
  float* dst = ze + (((size_t)(br0 * 32 + b)) * TT + t0 + i) * EE + j16;
  #pragma unroll
  for (int q = 0; q < 4; ++q)
    *(float4*)(dst + q*4) = *(float4*)&Cs[i][j16 + q*4];
}

// ---------------- K7: hyperbolic combine ----------------
__device__ __forceinline__ void mobius_add32(const float* x, const float* y, float* o) {
  float x2 = 0.f, y2 = 0.f, xy = 0.f;
  #pragma unroll
  for (int i = 0; i < 32; ++i) { x2 += x[i]*x[i]; y2 += y[i]*y[i]; xy += x[i]*y[i]; }
  float ca  = 1.f + 2.f*xy + y2;
  float cb  = 1.f - x2;
  float den = 1.f + 2.f*xy + x2*y2;
  float inv = 1.f / fmaxf(den, 1e-15f);
  #pragma unroll
  for (int i = 0; i < 32; ++i) o[i] = (ca*x[i] + cb*y[i]) * inv;
}

__global__ __launch_bounds__(256) void k_hyper(const float* __restrict__ ze,
                                               float* __restrict__ out) {
  int idx = blockIdx.x * 256 + threadIdx.x;
  int b = idx >> 10, t = idx & 1023;
  float v[4][32];
  #pragma unroll
  for (int br = 0; br < 4; ++br) {
    const float* p = ze + (((size_t)br * BB + b) * TT + t) * EE;
    float s = 0.f;
    #pragma unroll
    for (int e = 0; e < 32; ++e) { v[br][e] = p[e]; s += v[br][e]*v[br][e]; }
    float nr = sqrtf(fmaxf(s, 1e-15f));
    float sc = tanhf(nr) / nr;
    float s2 = 0.f;
    #pragma unroll
    for (int e = 0; e < 32; ++e) { v[br][e] *= sc; s2 += v[br][e]*v[br][e]; }
    float n2 = sqrtf(fmaxf(s2, 1e-15f));
    if (n2 > 0.996f) {
      float sc2 = 0.996f / n2;
      #pragma unroll
      for (int e = 0; e < 32; ++e) v[br][e] *= sc2;
    }
    float* o = out + (((size_t)br * BB + b) * TT + t) * EE;
    #pragma unroll
    for (int e = 0; e < 32; ++e) o[e] = v[br][e];
  }
  float m1[32], m2[32];
  mobius_add32(v[1], v[2], m1);
  mobius_add32(v[0], m1, m2);
  mobius_add32(m2, v[3], m1);
  float s = 0.f;
  #pragma unroll
  for (int e = 0; e < 32; ++e) s += m1[e]*m1[e];
  float n = sqrtf(fmaxf(s, 1e-15f));
  if (n > 0.996f) {
    float sc = 0.996f / n;
    #pragma unroll
    for (int e = 0; e < 32; ++e) m1[e] *= sc;
  }
  float* o = out + (((size_t)4 * BB + b) * TT + t) * EE;
  #pragma unroll
  for (int e = 0; e < 32; ++e) o[e] = m1[e];
}

// ---------------- host ----------------
extern "C" void kernel_launch(void* const* d_in, const int* in_sizes, int n_in,
                              void* d_out, int out_size, void* d_ws, size_t ws_size,
                              hipStream_t stream) {
  const float* xs0 = (const float*)d_in[0];
  const float* xs1 = (const float*)d_in[1];
  const float* xs2 = (const float*)d_in[2];
  const float* xs3 = (const float*)d_in[3];
  const float* inpW   = (const float*)d_in[4];
  const float* inpb   = (const float*)d_in[5];
  const float* iprojW = (const float*)d_in[6];
  const float* convW  = (const float*)d_in[7];
  const float* convb  = (const float*)d_in[8];
  const float* xprojW = (const float*)d_in[9];
  const float* dtW    = (const float*)d_in[10];
  const float* dtb    = (const float*)d_in[11];
  const float* A_log  = (const float*)d_in[12];
  const float* D_skip = (const float*)d_in[13];
  const float* outW   = (const float*)d_in[14];
  const float* outpW  = (const float*)d_in[15];
  const float* outpb  = (const float*)d_in[16];
  float* out = (float*)d_out;

  // pre-split weight buffers at the head of ws (ushort)
  const size_t wUshorts = 2 * (WXZ_N + WXD_N + WOUT_N);
  ushort* WxzH = (ushort*)d_ws;
  ushort* WxzL = WxzH + WXZ_N;
  ushort* WxdH = WxzL + WXZ_N;
  ushort* WxdL = WxdH + WXD_N;
  ushort* WoH  = WxdL + WXD_N;
  ushort* WoL  = WoH + WOUT_N;
  float* ws = (float*)(WoL + WOUT_N);

  const size_t zeF = (size_t)4 * BB * TT * EE;
  // per fused batch row: h 65536 (Hloc aliases its lower half) +
  // xr/zb/g/cd 4*131072 + Cm 16384 + sdt 2048
  const size_t perBl = 65536 + 4 * 131072 + 16384 + 2048;
  auto needBytes = [&](int NB) {
    return (zeF + (size_t)NB * 32 * perBl) * 4 + wUshorts * 2;
  };
  int NB = 4;
  if (needBytes(4) > ws_size) NB = 2;
  if (NB == 2 && needBytes(2) > ws_size) NB = 1;
  const int nbl = NB * 32;

  float* ze = ws;
  float* h  = ze + zeF;
  float* xr = h  + (size_t)nbl * 65536;
  float* zb = xr + (size_t)nbl * 131072;
  float* g  = zb + (size_t)nbl * 131072;   // y buffer
  float* cd = g  + (size_t)nbl * 131072;   // per-chunk dt-cumsum
  float* Cm = cd + (size_t)nbl * 131072;
  float* sdt = Cm + (size_t)nbl * 16384;
  float* Hloc = h;  // alias: Hloc dead before k_out writes h (r8+ structure)

  k_presplit<<<WXZ_N / 256, 256, 0, stream>>>(iprojW, xprojW, outW,
                                              WxzH, WxzL, WxdH, WxdL, WoH, WoL);

  for (int br0 = 0; br0 < 4; br0 += NB) {
    k_xz<<<dim3(16, nbl), 256, 0, stream>>>(xs0, xs1, xs2, xs3,
                                            WxzH, WxzL, inpW, inpb, xr, zb, br0);
    for (int l = 0; l < LL; ++l) {
      k_xds<<<dim3(16, nbl), 256, 0, stream>>>(xr, convW, convb, WxdH, WxdL,
                                               dtW, dtb, A_log, D_skip,
                                               cd, Cm, Hloc, g, sdt, br0, l);
      k_scan2<<<nbl * 60, 256, 0, stream>>>(cd, Cm, A_log, Hloc, sdt, g, br0, l);
      if (l < LL - 1)
        k_outxz<<<dim3(16, nbl), 256, 0, stream>>>(g, zb, WoH, WoL, WxzH, WxzL,
                                                   xr, br0, l);
      else
        k_out<<<dim3(16, nbl), 256, 0, stream>>>(g, zb, WoH, WoL, h, br0, l);
    }
    k_ze<<<dim3(8, nbl), 256, 0, stream>>>(h, outpW, outpb, ze, br0);
  }
  k_hyper<<<BB * TT / 256, 256, 0, stream>>>(ze, out);
}